// Round 4
// baseline (3630.050 us; speedup 1.0000x reference)
//
#include <hip/hip_runtime.h>
#include <hip/hip_bf16.h>
#include <math.h>

typedef __bf16 bf16;
typedef __bf16 bf16x8 __attribute__((ext_vector_type(8)));
typedef float  f32x4  __attribute__((ext_vector_type(4)));

#define LSTRIDE 40     // 32 + 8 pad halfwords; 80B rows keep 16B align, 2-way banks free
#define CLAMP(v) fminf(fmaxf((v), -100.f), 100.f)   // NaN tripwire; legit |v| <= ~40
#define NEGINF (-1e30f)

// ---------------- weight transpose + cast: dst_bf16[C][R] = src_f32[R][C] ----------------
__global__ __launch_bounds__(256)
void transpose_kernel(const float* __restrict__ src, bf16* __restrict__ dst, int R, int C)
{
    __shared__ float tile[32][33];
    int c0 = blockIdx.x * 32, r0 = blockIdx.y * 32;
    int tx = threadIdx.x, ty = threadIdx.y;   // block (32,8)
#pragma unroll
    for (int i = 0; i < 4; i++)
        tile[ty + i * 8][tx] = src[(long)(r0 + ty + i * 8) * C + c0 + tx];
    __syncthreads();
#pragma unroll
    for (int i = 0; i < 4; i++)
        dst[(long)(c0 + ty + i * 8) * R + r0 + tx] = (bf16)tile[tx][ty + i * 8];
}

// ---------------- layernorm (row per block, D=1024, 256 thr), f32 in -> bf16 out ----------------
__global__ __launch_bounds__(256)
void ln_kernel(const float* __restrict__ x, const float* __restrict__ w, const float* __restrict__ b,
               bf16* __restrict__ out)
{
    const int D = 1024;
    const long row = blockIdx.x;
    const int t = threadIdx.x;
    f32x4 xv = *(const f32x4*)(x + row * D + t * 4);
    float s  = xv[0] + xv[1] + xv[2] + xv[3];
    float s2 = xv[0] * xv[0] + xv[1] * xv[1] + xv[2] * xv[2] + xv[3] * xv[3];
#pragma unroll
    for (int off = 32; off; off >>= 1) { s += __shfl_xor(s, off); s2 += __shfl_xor(s2, off); }
    __shared__ float ls[4], ls2[4];
    if ((t & 63) == 0) { ls[t >> 6] = s; ls2[t >> 6] = s2; }
    __syncthreads();
    s = ls[0] + ls[1] + ls[2] + ls[3];
    s2 = ls2[0] + ls2[1] + ls2[2] + ls2[3];
    float mu = s / D;
    float var = fmaxf(s2 / D - mu * mu, 0.f);
    float rstd = rsqrtf(var + 1e-5f);
#pragma unroll
    for (int i = 0; i < 4; i++) {
        int c = t * 4 + i;
        float v = (xv[i] - mu) * rstd * w[c] + b[c];
        out[row * D + c] = (bf16)CLAMP(v);
    }
}

// ---------------- GEMM: C[M,N] = A[M,K] @ Bt[N,K]^T, 128x128 tile, bf16 MFMA ----------------
// MODE 0: out bf16 = clamp(acc)                               (qkv)
// MODE 1: out bf16 = clamp(relu(acc + bias_f32[n]))           (FFN inner)
// MODE 2: out f32  = clamp(acc + resid_f32[m,n])              (x1 = ctx@Wo + x)
// MODE 3: out f32  = clamp(acc + bias_f32[n] + resid_f32[m,n])(final out)
// MODE 4: out f32 += clamp(acc)                               (k-split accumulate)
template <int MODE>
__global__ __launch_bounds__(256)
void gemm_bt(const bf16* __restrict__ A, int lda, const bf16* __restrict__ Bt, int ldb,
             int M, int N, int K,
             const float* __restrict__ bias, const float* __restrict__ resid,
             void* __restrict__ outv, int ldo)
{
    __shared__ bf16 sA[128 * LSTRIDE];
    __shared__ bf16 sB[128 * LSTRIDE];
    const int t = threadIdx.x;
    const int wave = t >> 6, lane = t & 63;
    const int wr = wave >> 1, wc = wave & 1;      // 2x2 wave grid, 64x64 per wave
    const int quad = lane >> 4, l16 = lane & 15;
    const int bm = blockIdx.y * 128, bn = blockIdx.x * 128;
    const int srow = t >> 2;             // 0..63
    const int scg = (t & 3) * 8;         // 0,8,16,24

    f32x4 acc[4][4];
#pragma unroll
    for (int i = 0; i < 4; i++)
#pragma unroll
        for (int j = 0; j < 4; j++) acc[i][j] = f32x4{0.f, 0.f, 0.f, 0.f};

    const bf16* Ab = A + (long)bm * lda;
    const bf16* Bb = Bt + (long)bn * ldb;

    for (int k0 = 0; k0 < K; k0 += 32) {
        __syncthreads();
#pragma unroll
        for (int p = 0; p < 2; p++) {
            int r = p * 64 + srow;
            bf16x8 va = *(const bf16x8*)(Ab + (long)r * lda + k0 + scg);
            bf16x8 vb = *(const bf16x8*)(Bb + (long)r * ldb + k0 + scg);
            *(bf16x8*)(&sA[r * LSTRIDE + scg]) = va;
            *(bf16x8*)(&sB[r * LSTRIDE + scg]) = vb;
        }
        __syncthreads();
        bf16x8 af[4], bfv[4];
#pragma unroll
        for (int i = 0; i < 4; i++)
            af[i] = *(const bf16x8*)(&sA[(wr * 64 + i * 16 + l16) * LSTRIDE + quad * 8]);
#pragma unroll
        for (int j = 0; j < 4; j++)
            bfv[j] = *(const bf16x8*)(&sB[(wc * 64 + j * 16 + l16) * LSTRIDE + quad * 8]);
#pragma unroll
        for (int i = 0; i < 4; i++)
#pragma unroll
            for (int j = 0; j < 4; j++)
                acc[i][j] = __builtin_amdgcn_mfma_f32_16x16x32_bf16(af[i], bfv[j], acc[i][j], 0, 0, 0);
    }

    float bv[4];
    if constexpr (MODE == 1 || MODE == 3) {
#pragma unroll
        for (int j = 0; j < 4; j++) bv[j] = bias[bn + wc * 64 + j * 16 + l16];
    }
#pragma unroll
    for (int i = 0; i < 4; i++) {
        int m = bm + wr * 64 + i * 16 + quad * 4;
#pragma unroll
        for (int j = 0; j < 4; j++) {
            int n = bn + wc * 64 + j * 16 + l16;
#pragma unroll
            for (int r = 0; r < 4; r++) {
                float v = acc[i][j][r];
                long idx = (long)(m + r) * ldo + n;
                if constexpr (MODE == 0) {
                    ((bf16*)outv)[idx] = (bf16)CLAMP(v);
                } else if constexpr (MODE == 1) {
                    v += bv[j]; v = v > 0.f ? v : 0.f;
                    ((bf16*)outv)[idx] = (bf16)CLAMP(v);
                } else if constexpr (MODE == 2) {
                    ((float*)outv)[idx] = CLAMP(v + resid[idx]);
                } else if constexpr (MODE == 3) {
                    ((float*)outv)[idx] = CLAMP(v + bv[j] + resid[idx]);
                } else {   // MODE 4
                    ((float*)outv)[idx] += CLAMP(v);
                }
            }
        }
    }
}

// ---------------- naive (correct-by-construction) causal attention ----------------
// One query row per thread; K/V tiles (bf16) staged in LDS, broadcast reads.
__global__ __launch_bounds__(256)
void attn_naive(const bf16* __restrict__ qkv, bf16* __restrict__ ctx)
{
    const int s0 = blockIdx.x * 256;
    const int bh = blockIdx.y;
    const int b = bh >> 4, h = bh & 15;
    const int t = threadIdx.x;
    const int sq = s0 + t;                 // this thread's query row
    const long RS = 3072;
    const bf16* base = qkv + (long)b * 2048 * RS;
    __shared__ bf16 sK[64 * 72];
    __shared__ bf16 sV[64 * 72];

    float q[64], o[64];
    const bf16* qp = base + (long)sq * RS + h * 64;
#pragma unroll
    for (int d = 0; d < 64; d++) { q[d] = (float)qp[d]; o[d] = 0.f; }
    float m_i = NEGINF, l_i = 0.f;

    for (int kt = 0; kt <= s0 + 255; kt += 64) {
        __syncthreads();
        {   // stage K,V tile (rows kt..kt+63, natural [t][d], stride 72)
            int cg = (t & 7) * 8, rr = t >> 3;
#pragma unroll
            for (int p = 0; p < 2; p++) {
                int r = p * 32 + rr;
                *(bf16x8*)(&sK[r * 72 + cg]) = *(const bf16x8*)(base + (long)(kt + r) * RS + 1024 + h * 64 + cg);
                *(bf16x8*)(&sV[r * 72 + cg]) = *(const bf16x8*)(base + (long)(kt + r) * RS + 2048 + h * 64 + cg);
            }
        }
        __syncthreads();
        // pass 1: tile max over unmasked keys
        float mt = NEGINF;
        for (int tk = 0; tk < 64; tk++) {
            if (kt + tk > sq) break;
            float s = 0.f;
#pragma unroll
            for (int d = 0; d < 64; d++) s += q[d] * (float)sK[tk * 72 + d];
            mt = fmaxf(mt, s * 0.125f);
        }
        if (mt > -1e29f) {   // tile contributes
            float mn = fmaxf(m_i, mt);
            float alpha = __expf(m_i - mn);
            m_i = mn;
            l_i *= alpha;
#pragma unroll
            for (int d = 0; d < 64; d++) o[d] *= alpha;
            // pass 2: recompute scores, exp, accumulate PV
            for (int tk = 0; tk < 64; tk++) {
                if (kt + tk > sq) break;
                float s = 0.f;
#pragma unroll
                for (int d = 0; d < 64; d++) s += q[d] * (float)sK[tk * 72 + d];
                float p = __expf(s * 0.125f - m_i);
                l_i += p;
#pragma unroll
                for (int d = 0; d < 64; d++) o[d] += p * (float)sV[tk * 72 + d];
            }
        }
    }
    bf16* op = ctx + (long)(b * 2048 + sq) * 1024 + h * 64;
#pragma unroll
    for (int d = 0; d < 64; d++) op[d] = (bf16)CLAMP(o[d] / l_i);
}

// ---------------- confidence head (f32) ----------------
__global__ __launch_bounds__(256)
void conf_partial(const float* __restrict__ xout, const float* __restrict__ cw, float* __restrict__ part)
{
    int blk = blockIdx.x;           // 256 blocks: b = blk>>6, 32-row chunk
    int b = blk >> 6, chunk = blk & 63;
    int t = threadIdx.x;
    int d0 = t * 4;
    f32x4 w = *(const f32x4*)(cw + d0);
    float acc = 0.f;
    for (int s = chunk * 32; s < chunk * 32 + 32; s++) {
        f32x4 v = *(const f32x4*)(xout + (long)(b * 2048 + s) * 1024 + d0);
        acc += v[0] * w[0] + v[1] * w[1] + v[2] * w[2] + v[3] * w[3];
    }
#pragma unroll
    for (int off = 32; off; off >>= 1) acc += __shfl_xor(acc, off);
    __shared__ float ls[4];
    if ((t & 63) == 0) ls[t >> 6] = acc;
    __syncthreads();
    if (t == 0) part[blk] = ls[0] + ls[1] + ls[2] + ls[3];
}

__global__ void conf_final(const float* __restrict__ part, const float* __restrict__ cb, float* __restrict__ outp)
{
    if (threadIdx.x == 0) {
        float accb = 0.f;
        for (int b = 0; b < 4; b++) {
            float s = 0.f;
            for (int i = 0; i < 64; i++) s += part[b * 64 + i];
            float z = s / 2048.0f + cb[0];
            accb += 1.0f / (1.0f + expf(-z));
        }
        outp[0] = accb * 0.25f;
    }
}

// ---------------- launch ----------------
// All inputs f32 (per reference); internal activations bf16; residual chain f32.
// Workspace (1 MB = 1<<20), peak 96 MB + 1 KB, phase-disjoint aliasing:
//  [ 0, 8): WqkvT bf16 (6MB, ph1-3)  -> W1T bf16 (8MB, ph6+)
//  [ 8,16): WoT  bf16 (2MB, ph1-5)   -> W2T bf16 (8MB, ph6+)
//  [16,32): h bf16 (ph2-3) -> ctx bf16 (ph4-5) -> h2 bf16 (ph7-9)
//  [32,80): qkv bf16 [8192][3072] (ph3-4)
//  [32,64): x1 f32 [8192][1024] (ph5-10; qkv dead)
//  [64,96): a1h bf16 [8192][2048] (ph8-9)
//  [96MB):  part f32[256]
extern "C" void kernel_launch(void* const* d_in, const int* in_sizes, int n_in,
                              void* d_out, int out_size, void* d_ws, size_t ws_size,
                              hipStream_t stream)
{
    const int D = 1024, F = 4096, M = 8192;
    const size_t MB = 1u << 20;
    const float* x     = (const float*)d_in[0];
    const float* Wq    = (const float*)d_in[1];
    const float* Wk    = (const float*)d_in[2];
    const float* Wv    = (const float*)d_in[3];
    const float* Wo    = (const float*)d_in[4];
    const float* ln1w  = (const float*)d_in[5];
    const float* ln1b  = (const float*)d_in[6];
    const float* W1    = (const float*)d_in[7];
    const float* b1    = (const float*)d_in[8];
    const float* W2    = (const float*)d_in[9];
    const float* b2    = (const float*)d_in[10];
    const float* ln2w  = (const float*)d_in[11];
    const float* ln2b  = (const float*)d_in[12];
    const float* confw = (const float*)d_in[13];
    const float* confb = (const float*)d_in[14];
    float* out = (float*)d_out;

    char* ws = (char*)d_ws;
    bf16*  WqkvT = (bf16*)(ws);              // ph1-3
    bf16*  WoT   = (bf16*)(ws + 8 * MB);     // ph1-5
    bf16*  h     = (bf16*)(ws + 16 * MB);    // ph2-3
    bf16*  qkv   = (bf16*)(ws + 32 * MB);    // ph3-4
    bf16*  ctx   = (bf16*)(ws + 16 * MB);    // ph4-5
    float* x1    = (float*)(ws + 32 * MB);   // ph5-10 (qkv dead)
    bf16*  h2    = (bf16*)(ws + 16 * MB);    // ph7-9
    bf16*  W1T   = (bf16*)(ws);              // ph6+ (WqkvT dead)
    bf16*  W2T   = (bf16*)(ws + 8 * MB);     // ph6+ (WoT dead)
    bf16*  a1h   = (bf16*)(ws + 64 * MB);    // ph8-9
    float* part  = (float*)(ws + 96 * MB);

    dim3 tb(32, 8);
    // ph1: early weight transposes (+cast to bf16)
    transpose_kernel<<<dim3(D / 32, D / 32), tb, 0, stream>>>(Wq, WqkvT, D, D);
    transpose_kernel<<<dim3(D / 32, D / 32), tb, 0, stream>>>(Wk, WqkvT + (size_t)D * D, D, D);
    transpose_kernel<<<dim3(D / 32, D / 32), tb, 0, stream>>>(Wv, WqkvT + (size_t)2 * D * D, D, D);
    transpose_kernel<<<dim3(D / 32, D / 32), tb, 0, stream>>>(Wo, WoT, D, D);
    // ph2: LN1 (f32 x -> bf16 h)
    ln_kernel<<<M, 256, 0, stream>>>(x, ln1w, ln1b, h);
    // ph3: QKV projection
    gemm_bt<0><<<dim3(24, 64), 256, 0, stream>>>(h, D, WqkvT, D, M, 3 * D, D, nullptr, nullptr, qkv, 3 * D);
    // ph4: attention
    attn_naive<<<dim3(8, 64), 256, 0, stream>>>(qkv, ctx);
    // ph5: Wo projection + residual (f32 x) -> x1 f32
    gemm_bt<2><<<dim3(8, 64), 256, 0, stream>>>(ctx, D, WoT, D, M, D, D, nullptr, x, x1, D);
    // ph6: FFN weight transposes
    transpose_kernel<<<dim3(F / 32, D / 32), tb, 0, stream>>>(W1, W1T, D, F);
    transpose_kernel<<<dim3(D / 32, F / 32), tb, 0, stream>>>(W2, W2T, F, D);
    // ph7: LN2 (f32 x1 -> bf16 h2)
    ln_kernel<<<M, 256, 0, stream>>>(x1, ln2w, ln2b, h2);
    // ph8: FFN half 1
    gemm_bt<1><<<dim3(16, 64), 256, 0, stream>>>(h2, D, W1T, D, M, 2048, D, b1, nullptr, a1h, 2048);
    gemm_bt<4><<<dim3(8, 64), 256, 0, stream>>>(a1h, 2048, W2T, F, M, D, 2048, nullptr, nullptr, x1, D);
    // ph9: FFN half 2 -> out f32
    gemm_bt<1><<<dim3(16, 64), 256, 0, stream>>>(h2, D, W1T + (size_t)2048 * D, D, M, 2048, D, b1 + 2048, nullptr, a1h, 2048);
    gemm_bt<3><<<dim3(8, 64), 256, 0, stream>>>(a1h, 2048, W2T + 2048, F, M, D, 2048, b2, x1, out, D);
    // ph10: confidence head
    conf_partial<<<256, 256, 0, stream>>>(out, confw, part);
    conf_final<<<1, 64, 0, stream>>>(part, confb, out + (size_t)M * D);
}

// Round 5
// 783.563 us; speedup vs baseline: 4.6327x; 4.6327x over previous
//
#include <hip/hip_runtime.h>
#include <hip/hip_bf16.h>
#include <math.h>

typedef __bf16 bf16;
typedef __bf16 bf16x8 __attribute__((ext_vector_type(8)));
typedef float  f32x4  __attribute__((ext_vector_type(4)));

#define LSTRIDE 40     // 32 + 8 pad halfwords; 80B rows keep 16B align, 2-way banks free
#define CLAMP(v) fminf(fmaxf((v), -100.f), 100.f)   // NaN tripwire; legit |v| <= ~40
#define NEGINF (-1e30f)

// ---------------- weight transpose + cast: dst_bf16[C][R] = src_f32[R][C] ----------------
__global__ __launch_bounds__(256)
void transpose_kernel(const float* __restrict__ src, bf16* __restrict__ dst, int R, int C)
{
    __shared__ float tile[32][33];
    int c0 = blockIdx.x * 32, r0 = blockIdx.y * 32;
    int tx = threadIdx.x, ty = threadIdx.y;   // block (32,8)
#pragma unroll
    for (int i = 0; i < 4; i++)
        tile[ty + i * 8][tx] = src[(long)(r0 + ty + i * 8) * C + c0 + tx];
    __syncthreads();
#pragma unroll
    for (int i = 0; i < 4; i++)
        dst[(long)(c0 + ty + i * 8) * R + r0 + tx] = (bf16)tile[tx][ty + i * 8];
}

// ---------------- layernorm (row per block, D=1024, 256 thr), f32 in -> bf16 out ----------------
__global__ __launch_bounds__(256)
void ln_kernel(const float* __restrict__ x, const float* __restrict__ w, const float* __restrict__ b,
               bf16* __restrict__ out)
{
    const int D = 1024;
    const long row = blockIdx.x;
    const int t = threadIdx.x;
    f32x4 xv = *(const f32x4*)(x + row * D + t * 4);
    float s  = xv[0] + xv[1] + xv[2] + xv[3];
    float s2 = xv[0] * xv[0] + xv[1] * xv[1] + xv[2] * xv[2] + xv[3] * xv[3];
#pragma unroll
    for (int off = 32; off; off >>= 1) { s += __shfl_xor(s, off); s2 += __shfl_xor(s2, off); }
    __shared__ float ls[4], ls2[4];
    if ((t & 63) == 0) { ls[t >> 6] = s; ls2[t >> 6] = s2; }
    __syncthreads();
    s = ls[0] + ls[1] + ls[2] + ls[3];
    s2 = ls2[0] + ls2[1] + ls2[2] + ls2[3];
    float mu = s / D;
    float var = fmaxf(s2 / D - mu * mu, 0.f);
    float rstd = rsqrtf(var + 1e-5f);
#pragma unroll
    for (int i = 0; i < 4; i++) {
        int c = t * 4 + i;
        float v = (xv[i] - mu) * rstd * w[c] + b[c];
        out[row * D + c] = (bf16)CLAMP(v);
    }
}

// ---------------- GEMM: C[M,N] = A[M,K] @ Bt[N,K]^T, 128x128 tile, bf16 MFMA ----------------
// MODE 0: out bf16 = clamp(acc)                               (qkv)
// MODE 1: out bf16 = clamp(relu(acc + bias_f32[n]))           (FFN inner)
// MODE 2: out f32  = clamp(acc + resid_f32[m,n])              (x1 = ctx@Wo + x)
// MODE 3: out f32  = clamp(acc + bias_f32[n] + resid_f32[m,n])(final out)
// MODE 4: out f32 += clamp(acc)                               (k-split accumulate)
template <int MODE>
__global__ __launch_bounds__(256)
void gemm_bt(const bf16* __restrict__ A, int lda, const bf16* __restrict__ Bt, int ldb,
             int M, int N, int K,
             const float* __restrict__ bias, const float* __restrict__ resid,
             void* __restrict__ outv, int ldo)
{
    __shared__ bf16 sA[128 * LSTRIDE];
    __shared__ bf16 sB[128 * LSTRIDE];
    const int t = threadIdx.x;
    const int wave = t >> 6, lane = t & 63;
    const int wr = wave >> 1, wc = wave & 1;      // 2x2 wave grid, 64x64 per wave
    const int quad = lane >> 4, l16 = lane & 15;
    const int bm = blockIdx.y * 128, bn = blockIdx.x * 128;
    const int srow = t >> 2;             // 0..63
    const int scg = (t & 3) * 8;         // 0,8,16,24

    f32x4 acc[4][4];
#pragma unroll
    for (int i = 0; i < 4; i++)
#pragma unroll
        for (int j = 0; j < 4; j++) acc[i][j] = f32x4{0.f, 0.f, 0.f, 0.f};

    const bf16* Ab = A + (long)bm * lda;
    const bf16* Bb = Bt + (long)bn * ldb;

    for (int k0 = 0; k0 < K; k0 += 32) {
        __syncthreads();
#pragma unroll
        for (int p = 0; p < 2; p++) {
            int r = p * 64 + srow;
            bf16x8 va = *(const bf16x8*)(Ab + (long)r * lda + k0 + scg);
            bf16x8 vb = *(const bf16x8*)(Bb + (long)r * ldb + k0 + scg);
            *(bf16x8*)(&sA[r * LSTRIDE + scg]) = va;
            *(bf16x8*)(&sB[r * LSTRIDE + scg]) = vb;
        }
        __syncthreads();
        bf16x8 af[4], bfv[4];
#pragma unroll
        for (int i = 0; i < 4; i++)
            af[i] = *(const bf16x8*)(&sA[(wr * 64 + i * 16 + l16) * LSTRIDE + quad * 8]);
#pragma unroll
        for (int j = 0; j < 4; j++)
            bfv[j] = *(const bf16x8*)(&sB[(wc * 64 + j * 16 + l16) * LSTRIDE + quad * 8]);
#pragma unroll
        for (int i = 0; i < 4; i++)
#pragma unroll
            for (int j = 0; j < 4; j++)
                acc[i][j] = __builtin_amdgcn_mfma_f32_16x16x32_bf16(af[i], bfv[j], acc[i][j], 0, 0, 0);
    }

    float bv[4];
    if constexpr (MODE == 1 || MODE == 3) {
#pragma unroll
        for (int j = 0; j < 4; j++) bv[j] = bias[bn + wc * 64 + j * 16 + l16];
    }
#pragma unroll
    for (int i = 0; i < 4; i++) {
        int m = bm + wr * 64 + i * 16 + quad * 4;
#pragma unroll
        for (int j = 0; j < 4; j++) {
            int n = bn + wc * 64 + j * 16 + l16;
#pragma unroll
            for (int r = 0; r < 4; r++) {
                float v = acc[i][j][r];
                long idx = (long)(m + r) * ldo + n;
                if constexpr (MODE == 0) {
                    ((bf16*)outv)[idx] = (bf16)CLAMP(v);
                } else if constexpr (MODE == 1) {
                    v += bv[j]; v = v > 0.f ? v : 0.f;
                    ((bf16*)outv)[idx] = (bf16)CLAMP(v);
                } else if constexpr (MODE == 2) {
                    ((float*)outv)[idx] = CLAMP(v + resid[idx]);
                } else if constexpr (MODE == 3) {
                    ((float*)outv)[idx] = CLAMP(v + bv[j] + resid[idx]);
                } else {   // MODE 4
                    ((float*)outv)[idx] += CLAMP(v);
                }
            }
        }
    }
}

// ---------------- MFMA causal flash attention ----------------
// qkv: [B*S, 3072] rows; q at col h*64, k at 1024+h*64, v at 2048+h*64
// grid: (S/64, B*H); 4 waves, each owns 16 q rows.
// Layouts (HW-verified m89/m74): A[m=lane&15][k=quad*8+j]; B[k=quad*8+j][n=lane&15];
// C/D col=lane&15, row=quad*4+reg. P transform via per-wave LDS region (m120 pattern).
__global__ __launch_bounds__(256)
void attn_kernel(const bf16* __restrict__ qkv, bf16* __restrict__ ctx)
{
    const int s0 = blockIdx.x * 64;
    const int bh = blockIdx.y;
    const int b = bh >> 4, h = bh & 15;
    const int t = threadIdx.x;
    const int wave = t >> 6, lane = t & 63;
    const int quad = lane >> 4, l16 = lane & 15;
    const long RS = 3072;

    __shared__ bf16 sK[64 * 72];     // [t][d]
    __shared__ bf16 sVt[64 * 72];    // [d][t]
    __shared__ bf16 sP[4][16 * 72];  // per-wave [q_local][t_local]

    bf16x8 qf[2];
    {
        const bf16* qp = qkv + (long)(b * 2048 + s0 + wave * 16 + l16) * RS + h * 64 + quad * 8;
        qf[0] = *(const bf16x8*)(qp);
        qf[1] = *(const bf16x8*)(qp + 32);
    }
    f32x4 o[4];
#pragma unroll
    for (int j = 0; j < 4; j++) o[j] = f32x4{0.f, 0.f, 0.f, 0.f};
    float m_i[4], l_i[4];
#pragma unroll
    for (int r = 0; r < 4; r++) { m_i[r] = NEGINF; l_i[r] = 0.f; }
    const int q_row = s0 + wave * 16 + quad * 4;   // + r (C-layout rows)

    for (int t0 = 0; t0 <= s0; t0 += 64) {
        __syncthreads();
        {   // stage K natural [t][d], stride 72
            int cg = (t & 7) * 8;
#pragma unroll
            for (int p = 0; p < 2; p++) {
                int r = p * 32 + (t >> 3);
                *(bf16x8*)(&sK[r * 72 + cg]) =
                    *(const bf16x8*)(qkv + (long)(b * 2048 + t0 + r) * RS + 1024 + h * 64 + cg);
            }
        }
        {   // stage V transposed [d][t]; wave-coalesced scalar column reads
            int d = t & 63;
            int tg = (t >> 6) * 8;
#pragma unroll
            for (int p = 0; p < 2; p++) {
                int tb = p * 32 + tg;
                bf16x8 tmp;
#pragma unroll
                for (int i = 0; i < 8; i++)
                    tmp[i] = qkv[(long)(b * 2048 + t0 + tb + i) * RS + 2048 + h * 64 + d];
                *(bf16x8*)(&sVt[d * 72 + tb]) = tmp;
            }
        }
        __syncthreads();

        // scores: S(16x64) = Q(16x64) @ K^T
        f32x4 sc[4];
#pragma unroll
        for (int tt = 0; tt < 4; tt++) {
            f32x4 s4 = f32x4{0.f, 0.f, 0.f, 0.f};
            bf16x8 kf0 = *(const bf16x8*)(&sK[(tt * 16 + l16) * 72 + quad * 8]);
            bf16x8 kf1 = *(const bf16x8*)(&sK[(tt * 16 + l16) * 72 + 32 + quad * 8]);
            s4 = __builtin_amdgcn_mfma_f32_16x16x32_bf16(qf[0], kf0, s4, 0, 0, 0);
            s4 = __builtin_amdgcn_mfma_f32_16x16x32_bf16(qf[1], kf1, s4, 0, 0, 0);
            sc[tt] = s4;
        }
        // scale + causal mask + row max (finite mask; no inf arithmetic)
        float mtile[4];
#pragma unroll
        for (int r = 0; r < 4; r++) mtile[r] = NEGINF;
#pragma unroll
        for (int tt = 0; tt < 4; tt++) {
            int tcol = t0 + tt * 16 + l16;
#pragma unroll
            for (int r = 0; r < 4; r++) {
                float v = sc[tt][r] * 0.125f;
                v = (tcol > q_row + r) ? NEGINF : v;
                sc[tt][r] = v;
                mtile[r] = fmaxf(mtile[r], v);
            }
        }
#pragma unroll
        for (int r = 0; r < 4; r++) {
            float v = mtile[r];
            v = fmaxf(v, __shfl_xor(v, 1)); v = fmaxf(v, __shfl_xor(v, 2));
            v = fmaxf(v, __shfl_xor(v, 4)); v = fmaxf(v, __shfl_xor(v, 8));
            mtile[r] = v;
        }
        float alpha[4];
#pragma unroll
        for (int r = 0; r < 4; r++) {
            float mn = fmaxf(m_i[r], mtile[r]);
            alpha[r] = __expf(m_i[r] - mn);   // exp(<=0); first tile: exp(-inf-ish)=0
            m_i[r] = mn;
        }
        float lt[4] = {0.f, 0.f, 0.f, 0.f};
#pragma unroll
        for (int tt = 0; tt < 4; tt++)
#pragma unroll
            for (int r = 0; r < 4; r++) {
                float p = __expf(sc[tt][r] - m_i[r]);
                sc[tt][r] = p;
                lt[r] += p;
            }
#pragma unroll
        for (int r = 0; r < 4; r++) {
            float v = lt[r];
            v += __shfl_xor(v, 1); v += __shfl_xor(v, 2);
            v += __shfl_xor(v, 4); v += __shfl_xor(v, 8);
            l_i[r] = l_i[r] * alpha[r] + v;
        }
#pragma unroll
        for (int j = 0; j < 4; j++)
#pragma unroll
            for (int r = 0; r < 4; r++) o[j][r] *= alpha[r];
        // P: C-layout -> LDS -> A-layout (per-wave region; in-wave DS ordering)
#pragma unroll
        for (int tt = 0; tt < 4; tt++)
#pragma unroll
            for (int r = 0; r < 4; r++)
                sP[wave][(quad * 4 + r) * 72 + tt * 16 + l16] = (bf16)sc[tt][r];
        bf16x8 pf0 = *(const bf16x8*)(&sP[wave][l16 * 72 + quad * 8]);
        bf16x8 pf1 = *(const bf16x8*)(&sP[wave][l16 * 72 + 32 + quad * 8]);
#pragma unroll
        for (int j = 0; j < 4; j++) {
            bf16x8 vf0 = *(const bf16x8*)(&sVt[(j * 16 + l16) * 72 + quad * 8]);
            bf16x8 vf1 = *(const bf16x8*)(&sVt[(j * 16 + l16) * 72 + 32 + quad * 8]);
            o[j] = __builtin_amdgcn_mfma_f32_16x16x32_bf16(pf0, vf0, o[j], 0, 0, 0);
            o[j] = __builtin_amdgcn_mfma_f32_16x16x32_bf16(pf1, vf1, o[j], 0, 0, 0);
        }
    }
#pragma unroll
    for (int j = 0; j < 4; j++)
#pragma unroll
        for (int r = 0; r < 4; r++) {
            float v = o[j][r] / l_i[r];
            ctx[(long)(b * 2048 + q_row + r) * 1024 + h * 64 + j * 16 + l16] = (bf16)CLAMP(v);
        }
}

// ---------------- confidence head (f32) ----------------
__global__ __launch_bounds__(256)
void conf_partial(const float* __restrict__ xout, const float* __restrict__ cw, float* __restrict__ part)
{
    int blk = blockIdx.x;           // 256 blocks: b = blk>>6, 32-row chunk
    int b = blk >> 6, chunk = blk & 63;
    int t = threadIdx.x;
    int d0 = t * 4;
    f32x4 w = *(const f32x4*)(cw + d0);
    float acc = 0.f;
    for (int s = chunk * 32; s < chunk * 32 + 32; s++) {
        f32x4 v = *(const f32x4*)(xout + (long)(b * 2048 + s) * 1024 + d0);
        acc += v[0] * w[0] + v[1] * w[1] + v[2] * w[2] + v[3] * w[3];
    }
#pragma unroll
    for (int off = 32; off; off >>= 1) acc += __shfl_xor(acc, off);
    __shared__ float ls[4];
    if ((t & 63) == 0) ls[t >> 6] = acc;
    __syncthreads();
    if (t == 0) part[blk] = ls[0] + ls[1] + ls[2] + ls[3];
}

__global__ void conf_final(const float* __restrict__ part, const float* __restrict__ cb, float* __restrict__ outp)
{
    if (threadIdx.x == 0) {
        float accb = 0.f;
        for (int b = 0; b < 4; b++) {
            float s = 0.f;
            for (int i = 0; i < 64; i++) s += part[b * 64 + i];
            float z = s / 2048.0f + cb[0];
            accb += 1.0f / (1.0f + expf(-z));
        }
        outp[0] = accb * 0.25f;
    }
}

// ---------------- launch ----------------
// All inputs f32 (per reference); internal activations bf16; residual chain f32.
// Workspace (1 MB = 1<<20), peak 96 MB + 1 KB, phase-disjoint aliasing:
//  [ 0, 8): WqkvT bf16 (6MB, ph1-3)  -> W1T bf16 (8MB, ph6+)
//  [ 8,16): WoT  bf16 (2MB, ph1-5)   -> W2T bf16 (8MB, ph6+)
//  [16,32): h bf16 (ph2-3) -> ctx bf16 (ph4-5) -> h2 bf16 (ph7-9)
//  [32,80): qkv bf16 [8192][3072] (ph3-4)
//  [32,64): x1 f32 [8192][1024] (ph5-10; qkv dead)
//  [64,96): a1h bf16 [8192][2048] (ph8-9)
//  [96MB):  part f32[256]
extern "C" void kernel_launch(void* const* d_in, const int* in_sizes, int n_in,
                              void* d_out, int out_size, void* d_ws, size_t ws_size,
                              hipStream_t stream)
{
    const int D = 1024, F = 4096, M = 8192;
    const size_t MB = 1u << 20;
    const float* x     = (const float*)d_in[0];
    const float* Wq    = (const float*)d_in[1];
    const float* Wk    = (const float*)d_in[2];
    const float* Wv    = (const float*)d_in[3];
    const float* Wo    = (const float*)d_in[4];
    const float* ln1w  = (const float*)d_in[5];
    const float* ln1b  = (const float*)d_in[6];
    const float* W1    = (const float*)d_in[7];
    const float* b1    = (const float*)d_in[8];
    const float* W2    = (const float*)d_in[9];
    const float* b2    = (const float*)d_in[10];
    const float* ln2w  = (const float*)d_in[11];
    const float* ln2b  = (const float*)d_in[12];
    const float* confw = (const float*)d_in[13];
    const float* confb = (const float*)d_in[14];
    float* out = (float*)d_out;

    char* ws = (char*)d_ws;
    bf16*  WqkvT = (bf16*)(ws);              // ph1-3
    bf16*  WoT   = (bf16*)(ws + 8 * MB);     // ph1-5
    bf16*  h     = (bf16*)(ws + 16 * MB);    // ph2-3
    bf16*  qkv   = (bf16*)(ws + 32 * MB);    // ph3-4
    bf16*  ctx   = (bf16*)(ws + 16 * MB);    // ph4-5
    float* x1    = (float*)(ws + 32 * MB);   // ph5-10 (qkv dead)
    bf16*  h2    = (bf16*)(ws + 16 * MB);    // ph7-9
    bf16*  W1T   = (bf16*)(ws);              // ph6+ (WqkvT dead)
    bf16*  W2T   = (bf16*)(ws + 8 * MB);     // ph6+ (WoT dead)
    bf16*  a1h   = (bf16*)(ws + 64 * MB);    // ph8-9
    float* part  = (float*)(ws + 96 * MB);

    dim3 tb(32, 8);
    // ph1: early weight transposes (+cast to bf16)
    transpose_kernel<<<dim3(D / 32, D / 32), tb, 0, stream>>>(Wq, WqkvT, D, D);
    transpose_kernel<<<dim3(D / 32, D / 32), tb, 0, stream>>>(Wk, WqkvT + (size_t)D * D, D, D);
    transpose_kernel<<<dim3(D / 32, D / 32), tb, 0, stream>>>(Wv, WqkvT + (size_t)2 * D * D, D, D);
    transpose_kernel<<<dim3(D / 32, D / 32), tb, 0, stream>>>(Wo, WoT, D, D);
    // ph2: LN1 (f32 x -> bf16 h)
    ln_kernel<<<M, 256, 0, stream>>>(x, ln1w, ln1b, h);
    // ph3: QKV projection
    gemm_bt<0><<<dim3(24, 64), 256, 0, stream>>>(h, D, WqkvT, D, M, 3 * D, D, nullptr, nullptr, qkv, 3 * D);
    // ph4: attention (MFMA flash)
    attn_kernel<<<dim3(32, 64), 256, 0, stream>>>(qkv, ctx);
    // ph5: Wo projection + residual (f32 x) -> x1 f32
    gemm_bt<2><<<dim3(8, 64), 256, 0, stream>>>(ctx, D, WoT, D, M, D, D, nullptr, x, x1, D);
    // ph6: FFN weight transposes
    transpose_kernel<<<dim3(F / 32, D / 32), tb, 0, stream>>>(W1, W1T, D, F);
    transpose_kernel<<<dim3(D / 32, F / 32), tb, 0, stream>>>(W2, W2T, F, D);
    // ph7: LN2 (f32 x1 -> bf16 h2)
    ln_kernel<<<M, 256, 0, stream>>>(x1, ln2w, ln2b, h2);
    // ph8: FFN half 1
    gemm_bt<1><<<dim3(16, 64), 256, 0, stream>>>(h2, D, W1T, D, M, 2048, D, b1, nullptr, a1h, 2048);
    gemm_bt<4><<<dim3(8, 64), 256, 0, stream>>>(a1h, 2048, W2T, F, M, D, 2048, nullptr, nullptr, x1, D);
    // ph9: FFN half 2 -> out f32
    gemm_bt<1><<<dim3(16, 64), 256, 0, stream>>>(h2, D, W1T + (size_t)2048 * D, D, M, 2048, D, b1 + 2048, nullptr, a1h, 2048);
    gemm_bt<3><<<dim3(8, 64), 256, 0, stream>>>(a1h, 2048, W2T + 2048, F, M, D, 2048, b2, x1, out, D);
    // ph10: confidence head
    conf_partial<<<256, 256, 0, stream>>>(out, confw, part);
    conf_final<<<1, 64, 0, stream>>>(part, confb, out + (size_t)M * D);
}

// Round 7
// 751.166 us; speedup vs baseline: 4.8326x; 1.0431x over previous
//
#include <hip/hip_runtime.h>
#include <hip/hip_bf16.h>
#include <math.h>

typedef __bf16 bf16;
typedef __bf16 bf16x8 __attribute__((ext_vector_type(8)));
typedef float  f32x4  __attribute__((ext_vector_type(4)));

#define LSTRIDE 40     // 32 + 8 pad halfwords; 80B rows keep 16B align
#define CLAMP(v) fminf(fmaxf((v), -100.f), 100.f)   // NaN tripwire; legit |v| <= ~40
#define NEGINF (-1e30f)

// ---------------- 4x weight transpose + cast: dst_bf16[C][R] = src_f32[R][C], D x D ----------------
__global__ __launch_bounds__(256)
void transpose4_kernel(const float* __restrict__ Wq, const float* __restrict__ Wk,
                       const float* __restrict__ Wv, const float* __restrict__ Wo,
                       bf16* __restrict__ dstQKV, bf16* __restrict__ dstO)
{
    const int D = 1024;
    const float* src = (blockIdx.z == 0) ? Wq : (blockIdx.z == 1) ? Wk : (blockIdx.z == 2) ? Wv : Wo;
    bf16* dst = (blockIdx.z < 3) ? dstQKV + (size_t)blockIdx.z * D * D : dstO;
    __shared__ float tile[32][33];
    int c0 = blockIdx.x * 32, r0 = blockIdx.y * 32;
    int tx = threadIdx.x, ty = threadIdx.y;   // block (32,8)
#pragma unroll
    for (int i = 0; i < 4; i++)
        tile[ty + i * 8][tx] = src[(long)(r0 + ty + i * 8) * D + c0 + tx];
    __syncthreads();
#pragma unroll
    for (int i = 0; i < 4; i++)
        dst[(long)(c0 + ty + i * 8) * D + r0 + tx] = (bf16)tile[tx][ty + i * 8];
}

// ---------------- generic weight transpose + cast (W1/W2) ----------------
__global__ __launch_bounds__(256)
void transpose_kernel(const float* __restrict__ src, bf16* __restrict__ dst, int R, int C)
{
    __shared__ float tile[32][33];
    int c0 = blockIdx.x * 32, r0 = blockIdx.y * 32;
    int tx = threadIdx.x, ty = threadIdx.y;
#pragma unroll
    for (int i = 0; i < 4; i++)
        tile[ty + i * 8][tx] = src[(long)(r0 + ty + i * 8) * C + c0 + tx];
    __syncthreads();
#pragma unroll
    for (int i = 0; i < 4; i++)
        dst[(long)(c0 + ty + i * 8) * R + r0 + tx] = (bf16)tile[tx][ty + i * 8];
}

// ---------------- V transpose: Vt[bh][d][t] = qkv[(b*2048+t)*3072 + 2048 + h*64 + d] ----------------
__global__ __launch_bounds__(256)
void v_transpose(const bf16* __restrict__ qkv, bf16* __restrict__ Vt)
{
    __shared__ bf16 tile[32][33];
    int bh = blockIdx.z, b = bh >> 4, h = bh & 15;
    int t0 = blockIdx.x * 32, d0 = blockIdx.y * 32;
    int tx = threadIdx.x, ty = threadIdx.y;
#pragma unroll
    for (int i = 0; i < 4; i++)
        tile[ty + i * 8][tx] = qkv[(long)(b * 2048 + t0 + ty + i * 8) * 3072 + 2048 + h * 64 + d0 + tx];
    __syncthreads();
#pragma unroll
    for (int i = 0; i < 4; i++)
        Vt[((long)bh * 64 + d0 + ty + i * 8) * 2048 + t0 + tx] = tile[tx][ty + i * 8];
}

// ---------------- layernorm (row per block, D=1024, 256 thr), f32 in -> bf16 out ----------------
__global__ __launch_bounds__(256)
void ln_kernel(const float* __restrict__ x, const float* __restrict__ w, const float* __restrict__ b,
               bf16* __restrict__ out)
{
    const int D = 1024;
    const long row = blockIdx.x;
    const int t = threadIdx.x;
    f32x4 xv = *(const f32x4*)(x + row * D + t * 4);
    float s  = xv[0] + xv[1] + xv[2] + xv[3];
    float s2 = xv[0] * xv[0] + xv[1] * xv[1] + xv[2] * xv[2] + xv[3] * xv[3];
#pragma unroll
    for (int off = 32; off; off >>= 1) { s += __shfl_xor(s, off); s2 += __shfl_xor(s2, off); }
    __shared__ float ls[4], ls2[4];
    if ((t & 63) == 0) { ls[t >> 6] = s; ls2[t >> 6] = s2; }
    __syncthreads();
    s = ls[0] + ls[1] + ls[2] + ls[3];
    s2 = ls2[0] + ls2[1] + ls2[2] + ls2[3];
    float mu = s / D;
    float var = fmaxf(s2 / D - mu * mu, 0.f);
    float rstd = rsqrtf(var + 1e-5f);
#pragma unroll
    for (int i = 0; i < 4; i++) {
        int c = t * 4 + i;
        float v = (xv[i] - mu) * rstd * w[c] + b[c];
        out[row * D + c] = (bf16)CLAMP(v);
    }
}

// ---------------- GEMM: C[M,N] = A[M,K] @ Bt[N,K]^T, 128x128 tile, bf16 MFMA ----------------
// MODE 0: out bf16 = clamp(acc)                               (qkv)
// MODE 1: out bf16 = clamp(relu(acc + bias_f32[n]))           (FFN inner)
// MODE 2: out f32  = clamp(acc + resid_f32[m,n])              (x1 = ctx@Wo + x)
// MODE 3: out f32  = clamp(acc + bias_f32[n] + resid_f32[m,n])(final out)
// MODE 4: out f32 += clamp(acc)                               (k-split accumulate)
template <int MODE>
__global__ __launch_bounds__(256)
void gemm_bt(const bf16* __restrict__ A, int lda, const bf16* __restrict__ Bt, int ldb,
             int M, int N, int K,
             const float* __restrict__ bias, const float* __restrict__ resid,
             void* __restrict__ outv, int ldo)
{
    __shared__ bf16 sA[128 * LSTRIDE];
    __shared__ bf16 sB[128 * LSTRIDE];
    const int t = threadIdx.x;
    const int wave = t >> 6, lane = t & 63;
    const int wr = wave >> 1, wc = wave & 1;      // 2x2 wave grid, 64x64 per wave
    const int quad = lane >> 4, l16 = lane & 15;
    const int bm = blockIdx.y * 128, bn = blockIdx.x * 128;
    const int srow = t >> 2;             // 0..63
    const int scg = (t & 3) * 8;         // 0,8,16,24

    f32x4 acc[4][4];
#pragma unroll
    for (int i = 0; i < 4; i++)
#pragma unroll
        for (int j = 0; j < 4; j++) acc[i][j] = f32x4{0.f, 0.f, 0.f, 0.f};

    const bf16* Ab = A + (long)bm * lda;
    const bf16* Bb = Bt + (long)bn * ldb;

    for (int k0 = 0; k0 < K; k0 += 32) {
        __syncthreads();
#pragma unroll
        for (int p = 0; p < 2; p++) {
            int r = p * 64 + srow;
            bf16x8 va = *(const bf16x8*)(Ab + (long)r * lda + k0 + scg);
            bf16x8 vb = *(const bf16x8*)(Bb + (long)r * ldb + k0 + scg);
            *(bf16x8*)(&sA[r * LSTRIDE + scg]) = va;
            *(bf16x8*)(&sB[r * LSTRIDE + scg]) = vb;
        }
        __syncthreads();
        bf16x8 af[4], bfv[4];
#pragma unroll
        for (int i = 0; i < 4; i++)
            af[i] = *(const bf16x8*)(&sA[(wr * 64 + i * 16 + l16) * LSTRIDE + quad * 8]);
#pragma unroll
        for (int j = 0; j < 4; j++)
            bfv[j] = *(const bf16x8*)(&sB[(wc * 64 + j * 16 + l16) * LSTRIDE + quad * 8]);
#pragma unroll
        for (int i = 0; i < 4; i++)
#pragma unroll
            for (int j = 0; j < 4; j++)
                acc[i][j] = __builtin_amdgcn_mfma_f32_16x16x32_bf16(af[i], bfv[j], acc[i][j], 0, 0, 0);
    }

    float bv[4];
    if constexpr (MODE == 1 || MODE == 3) {
#pragma unroll
        for (int j = 0; j < 4; j++) bv[j] = bias[bn + wc * 64 + j * 16 + l16];
    }
#pragma unroll
    for (int i = 0; i < 4; i++) {
        int m = bm + wr * 64 + i * 16 + quad * 4;
#pragma unroll
        for (int j = 0; j < 4; j++) {
            int n = bn + wc * 64 + j * 16 + l16;
#pragma unroll
            for (int r = 0; r < 4; r++) {
                float v = acc[i][j][r];
                long idx = (long)(m + r) * ldo + n;
                if constexpr (MODE == 0) {
                    ((bf16*)outv)[idx] = (bf16)CLAMP(v);
                } else if constexpr (MODE == 1) {
                    v += bv[j]; v = v > 0.f ? v : 0.f;
                    ((bf16*)outv)[idx] = (bf16)CLAMP(v);
                } else if constexpr (MODE == 2) {
                    ((float*)outv)[idx] = CLAMP(v + resid[idx]);
                } else if constexpr (MODE == 3) {
                    ((float*)outv)[idx] = CLAMP(v + bv[j] + resid[idx]);
                } else {   // MODE 4
                    ((float*)outv)[idx] += CLAMP(v);
                }
            }
        }
    }
}

// ---------------- MFMA causal flash attention, Q-tile 128 ----------------
// qkv rows [B*S,3072] (q at h*64, k at 1024+h*64); Vt [bh][64][2048] pre-transposed.
// grid (16, 64): blockIdx.x = q-block (128 rows), blockIdx.y = bh. 4 waves, 32 q rows each.
// Register-prefetch pipeline across K-tiles.
__global__ __launch_bounds__(256)
void attn_kernel(const bf16* __restrict__ qkv, const bf16* __restrict__ Vt, bf16* __restrict__ ctx)
{
    const int qb = blockIdx.x;
    const int bh = blockIdx.y;
    const int b = bh >> 4, h = bh & 15;
    const int t = threadIdx.x;
    const int wave = t >> 6, lane = t & 63;
    const int quad = lane >> 4, l16 = lane & 15;
    const long RS = 3072;
    const int ntiles = 2 * qb + 2;

    __shared__ bf16 sK[64 * 72];      // [t][d]
    __shared__ bf16 sVt[64 * 72];     // [d][t]
    __shared__ bf16 sP[4][32 * 72];   // per-wave [q_local 32][t_local]

    // Q fragments: rows qb*128 + wave*32 + rf*16 + l16
    bf16x8 qf[2][2];
#pragma unroll
    for (int rf = 0; rf < 2; rf++) {
        const bf16* qp = qkv + (long)(b * 2048 + qb * 128 + wave * 32 + rf * 16 + l16) * RS + h * 64 + quad * 8;
        qf[rf][0] = *(const bf16x8*)(qp);
        qf[rf][1] = *(const bf16x8*)(qp + 32);
    }
    f32x4 o[2][4];
    float m_i[2][4], l_i[2][4];
#pragma unroll
    for (int rf = 0; rf < 2; rf++) {
#pragma unroll
        for (int j = 0; j < 4; j++) o[rf][j] = f32x4{0.f, 0.f, 0.f, 0.f};
#pragma unroll
        for (int r = 0; r < 4; r++) { m_i[rf][r] = NEGINF; l_i[rf][r] = 0.f; }
    }
    const int qrow0 = qb * 128 + wave * 32 + quad * 4;   // + rf*16 + r

    // staging indices: cg = (t&7)*8 halfword col group, rr = t>>3 row
    const int cg = (t & 7) * 8, rr = t >> 3;
    const bf16* Kbase  = qkv + (long)(b * 2048) * RS + 1024 + h * 64;
    const bf16* Vtbase = Vt + ((long)bh * 64) * 2048;

    bf16x8 kreg[2], vreg[2];
#pragma unroll
    for (int p = 0; p < 2; p++) {   // prefetch tile 0
        kreg[p] = *(const bf16x8*)(Kbase + (long)(p * 32 + rr) * RS + cg);
        vreg[p] = *(const bf16x8*)(Vtbase + (long)(p * 32 + rr) * 2048 + cg);
    }

    for (int ti = 0; ti < ntiles; ti++) {
        __syncthreads();   // previous tile's compute done; LDS reusable
#pragma unroll
        for (int p = 0; p < 2; p++) {
            *(bf16x8*)(&sK[(p * 32 + rr) * 72 + cg]) = kreg[p];
            *(bf16x8*)(&sVt[(p * 32 + rr) * 72 + cg]) = vreg[p];
        }
        __syncthreads();
        if (ti + 1 < ntiles) {   // prefetch next tile; latency overlaps compute below
            int t0n = (ti + 1) * 64;
#pragma unroll
            for (int p = 0; p < 2; p++) {
                kreg[p] = *(const bf16x8*)(Kbase + (long)(t0n + p * 32 + rr) * RS + cg);
                // Vt is [d][t]: tile index offsets the COLUMN (t), row stays d = p*32+rr
                vreg[p] = *(const bf16x8*)(Vtbase + (long)(p * 32 + rr) * 2048 + t0n + cg);
            }
        }
        const int t0 = ti * 64;

        // K fragments (shared across rf)
        bf16x8 kf[4][2];
#pragma unroll
        for (int tt = 0; tt < 4; tt++) {
            kf[tt][0] = *(const bf16x8*)(&sK[(tt * 16 + l16) * 72 + quad * 8]);
            kf[tt][1] = *(const bf16x8*)(&sK[(tt * 16 + l16) * 72 + 32 + quad * 8]);
        }
        // scores + online softmax per row-fragment
        f32x4 sc[2][4];
#pragma unroll
        for (int rf = 0; rf < 2; rf++) {
#pragma unroll
            for (int tt = 0; tt < 4; tt++) {
                f32x4 s4 = f32x4{0.f, 0.f, 0.f, 0.f};
                s4 = __builtin_amdgcn_mfma_f32_16x16x32_bf16(qf[rf][0], kf[tt][0], s4, 0, 0, 0);
                s4 = __builtin_amdgcn_mfma_f32_16x16x32_bf16(qf[rf][1], kf[tt][1], s4, 0, 0, 0);
                sc[rf][tt] = s4;
            }
            float mtile[4];
#pragma unroll
            for (int r = 0; r < 4; r++) mtile[r] = NEGINF;
#pragma unroll
            for (int tt = 0; tt < 4; tt++) {
                int tcol = t0 + tt * 16 + l16;
#pragma unroll
                for (int r = 0; r < 4; r++) {
                    float v = sc[rf][tt][r] * 0.125f;
                    v = (tcol > qrow0 + rf * 16 + r) ? NEGINF : v;
                    sc[rf][tt][r] = v;
                    mtile[r] = fmaxf(mtile[r], v);
                }
            }
#pragma unroll
            for (int r = 0; r < 4; r++) {
                float v = mtile[r];
                v = fmaxf(v, __shfl_xor(v, 1)); v = fmaxf(v, __shfl_xor(v, 2));
                v = fmaxf(v, __shfl_xor(v, 4)); v = fmaxf(v, __shfl_xor(v, 8));
                mtile[r] = v;
            }
            float alpha[4];
#pragma unroll
            for (int r = 0; r < 4; r++) {
                float mn = fmaxf(m_i[rf][r], mtile[r]);
                alpha[r] = __expf(m_i[rf][r] - mn);
                m_i[rf][r] = mn;
            }
            float lt[4] = {0.f, 0.f, 0.f, 0.f};
#pragma unroll
            for (int tt = 0; tt < 4; tt++)
#pragma unroll
                for (int r = 0; r < 4; r++) {
                    float p = __expf(sc[rf][tt][r] - m_i[rf][r]);
                    sc[rf][tt][r] = p;
                    lt[r] += p;
                }
#pragma unroll
            for (int r = 0; r < 4; r++) {
                float v = lt[r];
                v += __shfl_xor(v, 1); v += __shfl_xor(v, 2);
                v += __shfl_xor(v, 4); v += __shfl_xor(v, 8);
                l_i[rf][r] = l_i[rf][r] * alpha[r] + v;
            }
#pragma unroll
            for (int j = 0; j < 4; j++)
#pragma unroll
                for (int r = 0; r < 4; r++) o[rf][j][r] *= alpha[r];
            // P: C-layout -> per-wave LDS -> A-layout
#pragma unroll
            for (int tt = 0; tt < 4; tt++)
#pragma unroll
                for (int r = 0; r < 4; r++)
                    sP[wave][(rf * 16 + quad * 4 + r) * 72 + tt * 16 + l16] = (bf16)sc[rf][tt][r];
        }
        // PV: V fragments shared across rf
#pragma unroll
        for (int j = 0; j < 4; j++) {
            bf16x8 vf0 = *(const bf16x8*)(&sVt[(j * 16 + l16) * 72 + quad * 8]);
            bf16x8 vf1 = *(const bf16x8*)(&sVt[(j * 16 + l16) * 72 + 32 + quad * 8]);
#pragma unroll
            for (int rf = 0; rf < 2; rf++) {
                bf16x8 pf0 = *(const bf16x8*)(&sP[wave][(rf * 16 + l16) * 72 + quad * 8]);
                bf16x8 pf1 = *(const bf16x8*)(&sP[wave][(rf * 16 + l16) * 72 + 32 + quad * 8]);
                o[rf][j] = __builtin_amdgcn_mfma_f32_16x16x32_bf16(pf0, vf0, o[rf][j], 0, 0, 0);
                o[rf][j] = __builtin_amdgcn_mfma_f32_16x16x32_bf16(pf1, vf1, o[rf][j], 0, 0, 0);
            }
        }
    }
#pragma unroll
    for (int rf = 0; rf < 2; rf++)
#pragma unroll
        for (int j = 0; j < 4; j++)
#pragma unroll
            for (int r = 0; r < 4; r++) {
                float v = o[rf][j][r] / l_i[rf][r];
                ctx[(long)(b * 2048 + qrow0 + rf * 16 + r) * 1024 + h * 64 + j * 16 + l16] = (bf16)CLAMP(v);
            }
}

// ---------------- confidence head (f32) ----------------
__global__ __launch_bounds__(256)
void conf_partial(const float* __restrict__ xout, const float* __restrict__ cw, float* __restrict__ part)
{
    int blk = blockIdx.x;
    int b = blk >> 6, chunk = blk & 63;
    int t = threadIdx.x;
    int d0 = t * 4;
    f32x4 w = *(const f32x4*)(cw + d0);
    float acc = 0.f;
    for (int s = chunk * 32; s < chunk * 32 + 32; s++) {
        f32x4 v = *(const f32x4*)(xout + (long)(b * 2048 + s) * 1024 + d0);
        acc += v[0] * w[0] + v[1] * w[1] + v[2] * w[2] + v[3] * w[3];
    }
#pragma unroll
    for (int off = 32; off; off >>= 1) acc += __shfl_xor(acc, off);
    __shared__ float ls[4];
    if ((t & 63) == 0) ls[t >> 6] = acc;
    __syncthreads();
    if (t == 0) part[blk] = ls[0] + ls[1] + ls[2] + ls[3];
}

__global__ void conf_final(const float* __restrict__ part, const float* __restrict__ cb, float* __restrict__ outp)
{
    if (threadIdx.x == 0) {
        float accb = 0.f;
        for (int b = 0; b < 4; b++) {
            float s = 0.f;
            for (int i = 0; i < 64; i++) s += part[b * 64 + i];
            float z = s / 2048.0f + cb[0];
            accb += 1.0f / (1.0f + expf(-z));
        }
        outp[0] = accb * 0.25f;
    }
}

// ---------------- launch ----------------
// Workspace (1 MB = 1<<20), peak 96 MB + 1 KB, phase-disjoint aliasing:
//  [ 0, 8): WqkvT (ph1-3) -> W1T (ph6+)
//  [ 8,16): WoT (ph1-5)   -> W2T (ph6+)
//  [16,32): h (ph2-3) -> ctx (ph4-5) -> h2 (ph7-9)
//  [32,80): qkv (ph3-4); x1 f32 [32,64) ph5+ (qkv dead)
//  [80,96): Vt (ph3.5-4); a1h [64,96) ph8-9 (qkv tail + Vt dead)
//  [96MB):  part f32[256]
extern "C" void kernel_launch(void* const* d_in, const int* in_sizes, int n_in,
                              void* d_out, int out_size, void* d_ws, size_t ws_size,
                              hipStream_t stream)
{
    const int D = 1024, F = 4096, M = 8192;
    const size_t MB = 1u << 20;
    const float* x     = (const float*)d_in[0];
    const float* Wq    = (const float*)d_in[1];
    const float* Wk    = (const float*)d_in[2];
    const float* Wv    = (const float*)d_in[3];
    const float* Wo    = (const float*)d_in[4];
    const float* ln1w  = (const float*)d_in[5];
    const float* ln1b  = (const float*)d_in[6];
    const float* W1    = (const float*)d_in[7];
    const float* b1    = (const float*)d_in[8];
    const float* W2    = (const float*)d_in[9];
    const float* b2    = (const float*)d_in[10];
    const float* ln2w  = (const float*)d_in[11];
    const float* ln2b  = (const float*)d_in[12];
    const float* confw = (const float*)d_in[13];
    const float* confb = (const float*)d_in[14];
    float* out = (float*)d_out;

    char* ws = (char*)d_ws;
    bf16*  WqkvT = (bf16*)(ws);
    bf16*  WoT   = (bf16*)(ws + 8 * MB);
    bf16*  h     = (bf16*)(ws + 16 * MB);
    bf16*  qkv   = (bf16*)(ws + 32 * MB);
    bf16*  Vt    = (bf16*)(ws + 80 * MB);
    bf16*  ctx   = (bf16*)(ws + 16 * MB);
    float* x1    = (float*)(ws + 32 * MB);
    bf16*  h2    = (bf16*)(ws + 16 * MB);
    bf16*  W1T   = (bf16*)(ws);
    bf16*  W2T   = (bf16*)(ws + 8 * MB);
    bf16*  a1h   = (bf16*)(ws + 64 * MB);
    float* part  = (float*)(ws + 96 * MB);

    dim3 tb(32, 8);
    // ph1: QKV/Wo weight transposes in one launch
    transpose4_kernel<<<dim3(32, 32, 4), tb, 0, stream>>>(Wq, Wk, Wv, Wo, WqkvT, WoT);
    // ph2: LN1
    ln_kernel<<<M, 256, 0, stream>>>(x, ln1w, ln1b, h);
    // ph3: QKV projection
    gemm_bt<0><<<dim3(24, 64), 256, 0, stream>>>(h, D, WqkvT, D, M, 3 * D, D, nullptr, nullptr, qkv, 3 * D);
    // ph3.5: V transpose
    v_transpose<<<dim3(64, 2, 64), tb, 0, stream>>>(qkv, Vt);
    // ph4: attention (MFMA flash, Q-tile 128, prefetch pipeline)
    attn_kernel<<<dim3(16, 64), 256, 0, stream>>>(qkv, Vt, ctx);
    // ph5: Wo projection + residual -> x1 f32
    gemm_bt<2><<<dim3(8, 64), 256, 0, stream>>>(ctx, D, WoT, D, M, D, D, nullptr, x, x1, D);
    // ph6: FFN weight transposes
    transpose_kernel<<<dim3(F / 32, D / 32), tb, 0, stream>>>(W1, W1T, D, F);
    transpose_kernel<<<dim3(D / 32, F / 32), tb, 0, stream>>>(W2, W2T, F, D);
    // ph7: LN2
    ln_kernel<<<M, 256, 0, stream>>>(x1, ln2w, ln2b, h2);
    // ph8: FFN half 1
    gemm_bt<1><<<dim3(16, 64), 256, 0, stream>>>(h2, D, W1T, D, M, 2048, D, b1, nullptr, a1h, 2048);
    gemm_bt<4><<<dim3(8, 64), 256, 0, stream>>>(a1h, 2048, W2T, F, M, D, 2048, nullptr, nullptr, x1, D);
    // ph9: FFN half 2 -> out f32
    gemm_bt<1><<<dim3(16, 64), 256, 0, stream>>>(h2, D, W1T + (size_t)2048 * D, D, M, 2048, D, b1 + 2048, nullptr, a1h, 2048);
    gemm_bt<3><<<dim3(8, 64), 256, 0, stream>>>(a1h, 2048, W2T + 2048, F, M, D, 2048, b2, x1, out, D);
    // ph10: confidence head
    conf_partial<<<256, 256, 0, stream>>>(out, confw, part);
    conf_final<<<1, 64, 0, stream>>>(part, confb, out + (size_t)M * D);
}

// Round 8
// 641.839 us; speedup vs baseline: 5.6557x; 1.1703x over previous
//
#include <hip/hip_runtime.h>
#include <hip/hip_bf16.h>
#include <math.h>

typedef __bf16 bf16;
typedef __bf16 bf16x8 __attribute__((ext_vector_type(8)));
typedef __bf16 bf16x4 __attribute__((ext_vector_type(4)));
typedef float  f32x4  __attribute__((ext_vector_type(4)));
typedef short  s16x4  __attribute__((ext_vector_type(4)));

#define LSTRIDE 40     // 32 + 8 pad halfwords; 80B rows keep 16B align
#define CLAMP(v) fminf(fmaxf((v), -100.f), 100.f)   // NaN tripwire; legit |v| <= ~40
#define NEGINF (-1e30f)

// K=16 bf16 MFMA (PV stage): builtin name differs across ROCm versions
static __device__ __forceinline__ f32x4 mfma16(bf16x4 a, bf16x4 b, f32x4 c)
{
#if __has_builtin(__builtin_amdgcn_mfma_f32_16x16x16_bf16)
    return __builtin_amdgcn_mfma_f32_16x16x16_bf16(a, b, c, 0, 0, 0);
#else
    s16x4 as, bs;
    __builtin_memcpy(&as, &a, 8);
    __builtin_memcpy(&bs, &b, 8);
    return __builtin_amdgcn_mfma_f32_16x16x16bf16_1k(as, bs, c, 0, 0, 0);
#endif
}

// ---------------- 4x weight transpose + cast: dst_bf16[C][R] = src_f32[R][C], D x D ----------------
__global__ __launch_bounds__(256)
void transpose4_kernel(const float* __restrict__ Wq, const float* __restrict__ Wk,
                       const float* __restrict__ Wv, const float* __restrict__ Wo,
                       bf16* __restrict__ dstQKV, bf16* __restrict__ dstO)
{
    const int D = 1024;
    const float* src = (blockIdx.z == 0) ? Wq : (blockIdx.z == 1) ? Wk : (blockIdx.z == 2) ? Wv : Wo;
    bf16* dst = (blockIdx.z < 3) ? dstQKV + (size_t)blockIdx.z * D * D : dstO;
    __shared__ float tile[32][33];
    int c0 = blockIdx.x * 32, r0 = blockIdx.y * 32;
    int tx = threadIdx.x, ty = threadIdx.y;   // block (32,8)
#pragma unroll
    for (int i = 0; i < 4; i++)
        tile[ty + i * 8][tx] = src[(long)(r0 + ty + i * 8) * D + c0 + tx];
    __syncthreads();
#pragma unroll
    for (int i = 0; i < 4; i++)
        dst[(long)(c0 + ty + i * 8) * D + r0 + tx] = (bf16)tile[tx][ty + i * 8];
}

// ---------------- generic weight transpose + cast (W1/W2) ----------------
__global__ __launch_bounds__(256)
void transpose_kernel(const float* __restrict__ src, bf16* __restrict__ dst, int R, int C)
{
    __shared__ float tile[32][33];
    int c0 = blockIdx.x * 32, r0 = blockIdx.y * 32;
    int tx = threadIdx.x, ty = threadIdx.y;
#pragma unroll
    for (int i = 0; i < 4; i++)
        tile[ty + i * 8][tx] = src[(long)(r0 + ty + i * 8) * C + c0 + tx];
    __syncthreads();
#pragma unroll
    for (int i = 0; i < 4; i++)
        dst[(long)(c0 + ty + i * 8) * R + r0 + tx] = (bf16)tile[tx][ty + i * 8];
}

// ---------------- V transpose: Vt[bh][d][t] = qkv[(b*2048+t)*3072 + 2048 + h*64 + d] ----------------
__global__ __launch_bounds__(256)
void v_transpose(const bf16* __restrict__ qkv, bf16* __restrict__ Vt)
{
    __shared__ bf16 tile[32][33];
    int bh = blockIdx.z, b = bh >> 4, h = bh & 15;
    int t0 = blockIdx.x * 32, d0 = blockIdx.y * 32;
    int tx = threadIdx.x, ty = threadIdx.y;
#pragma unroll
    for (int i = 0; i < 4; i++)
        tile[ty + i * 8][tx] = qkv[(long)(b * 2048 + t0 + ty + i * 8) * 3072 + 2048 + h * 64 + d0 + tx];
    __syncthreads();
#pragma unroll
    for (int i = 0; i < 4; i++)
        Vt[((long)bh * 64 + d0 + ty + i * 8) * 2048 + t0 + tx] = tile[tx][ty + i * 8];
}

// ---------------- layernorm (row per block, D=1024, 256 thr), f32 in -> bf16 out ----------------
__global__ __launch_bounds__(256)
void ln_kernel(const float* __restrict__ x, const float* __restrict__ w, const float* __restrict__ b,
               bf16* __restrict__ out)
{
    const int D = 1024;
    const long row = blockIdx.x;
    const int t = threadIdx.x;
    f32x4 xv = *(const f32x4*)(x + row * D + t * 4);
    float s  = xv[0] + xv[1] + xv[2] + xv[3];
    float s2 = xv[0] * xv[0] + xv[1] * xv[1] + xv[2] * xv[2] + xv[3] * xv[3];
#pragma unroll
    for (int off = 32; off; off >>= 1) { s += __shfl_xor(s, off); s2 += __shfl_xor(s2, off); }
    __shared__ float ls[4], ls2[4];
    if ((t & 63) == 0) { ls[t >> 6] = s; ls2[t >> 6] = s2; }
    __syncthreads();
    s = ls[0] + ls[1] + ls[2] + ls[3];
    s2 = ls2[0] + ls2[1] + ls2[2] + ls2[3];
    float mu = s / D;
    float var = fmaxf(s2 / D - mu * mu, 0.f);
    float rstd = rsqrtf(var + 1e-5f);
#pragma unroll
    for (int i = 0; i < 4; i++) {
        int c = t * 4 + i;
        float v = (xv[i] - mu) * rstd * w[c] + b[c];
        out[row * D + c] = (bf16)CLAMP(v);
    }
}

// ---------------- GEMM: C[M,N] = A[M,K] @ Bt[N,K]^T, 128x128 tile, bf16 MFMA ----------------
// MODE 0: out bf16 = clamp(acc)                               (qkv)
// MODE 1: out bf16 = clamp(relu(acc + bias_f32[n]))           (FFN inner)
// MODE 2: out f32  = clamp(acc + resid_f32[m,n])              (x1 = ctx@Wo + x)
// MODE 3: out f32  = clamp(acc + bias_f32[n] + resid_f32[m,n])(final out)
// MODE 4: out f32 += clamp(acc)                               (k-split accumulate)
template <int MODE>
__global__ __launch_bounds__(256)
void gemm_bt(const bf16* __restrict__ A, int lda, const bf16* __restrict__ Bt, int ldb,
             int M, int N, int K,
             const float* __restrict__ bias, const float* __restrict__ resid,
             void* __restrict__ outv, int ldo)
{
    __shared__ bf16 sA[128 * LSTRIDE];
    __shared__ bf16 sB[128 * LSTRIDE];
    const int t = threadIdx.x;
    const int wave = t >> 6, lane = t & 63;
    const int wr = wave >> 1, wc = wave & 1;      // 2x2 wave grid, 64x64 per wave
    const int quad = lane >> 4, l16 = lane & 15;
    const int bm = blockIdx.y * 128, bn = blockIdx.x * 128;
    const int srow = t >> 2;             // 0..63
    const int scg = (t & 3) * 8;         // 0,8,16,24

    f32x4 acc[4][4];
#pragma unroll
    for (int i = 0; i < 4; i++)
#pragma unroll
        for (int j = 0; j < 4; j++) acc[i][j] = f32x4{0.f, 0.f, 0.f, 0.f};

    const bf16* Ab = A + (long)bm * lda;
    const bf16* Bb = Bt + (long)bn * ldb;

    for (int k0 = 0; k0 < K; k0 += 32) {
        __syncthreads();
#pragma unroll
        for (int p = 0; p < 2; p++) {
            int r = p * 64 + srow;
            bf16x8 va = *(const bf16x8*)(Ab + (long)r * lda + k0 + scg);
            bf16x8 vb = *(const bf16x8*)(Bb + (long)r * ldb + k0 + scg);
            *(bf16x8*)(&sA[r * LSTRIDE + scg]) = va;
            *(bf16x8*)(&sB[r * LSTRIDE + scg]) = vb;
        }
        __syncthreads();
        bf16x8 af[4], bfv[4];
#pragma unroll
        for (int i = 0; i < 4; i++)
            af[i] = *(const bf16x8*)(&sA[(wr * 64 + i * 16 + l16) * LSTRIDE + quad * 8]);
#pragma unroll
        for (int j = 0; j < 4; j++)
            bfv[j] = *(const bf16x8*)(&sB[(wc * 64 + j * 16 + l16) * LSTRIDE + quad * 8]);
#pragma unroll
        for (int i = 0; i < 4; i++)
#pragma unroll
            for (int j = 0; j < 4; j++)
                acc[i][j] = __builtin_amdgcn_mfma_f32_16x16x32_bf16(af[i], bfv[j], acc[i][j], 0, 0, 0);
    }

    float bv[4];
    if constexpr (MODE == 1 || MODE == 3) {
#pragma unroll
        for (int j = 0; j < 4; j++) bv[j] = bias[bn + wc * 64 + j * 16 + l16];
    }
#pragma unroll
    for (int i = 0; i < 4; i++) {
        int m = bm + wr * 64 + i * 16 + quad * 4;
#pragma unroll
        for (int j = 0; j < 4; j++) {
            int n = bn + wc * 64 + j * 16 + l16;
#pragma unroll
            for (int r = 0; r < 4; r++) {
                float v = acc[i][j][r];
                long idx = (long)(m + r) * ldo + n;
                if constexpr (MODE == 0) {
                    ((bf16*)outv)[idx] = (bf16)CLAMP(v);
                } else if constexpr (MODE == 1) {
                    v += bv[j]; v = v > 0.f ? v : 0.f;
                    ((bf16*)outv)[idx] = (bf16)CLAMP(v);
                } else if constexpr (MODE == 2) {
                    ((float*)outv)[idx] = CLAMP(v + resid[idx]);
                } else if constexpr (MODE == 3) {
                    ((float*)outv)[idx] = CLAMP(v + bv[j] + resid[idx]);
                } else {   // MODE 4
                    ((float*)outv)[idx] += CLAMP(v);
                }
            }
        }
    }
}

// ---------------- MFMA causal flash attention, S^T formulation ----------------
// S^T = K·Q^T via mfma(A=K_frag, B=Q_frag): lanes hold q=l16, t=quad*4+r (+16*tt).
// Softmax state per-lane scalar (q=l16); reductions = 2 shuffles (xor 16,32).
// PV: O^T = V^T·P^T via mfma_16x16x16: P^T C-layout == B-operand layout (k=quad*4+j),
// zero data movement; V^T A-frags are b64 reads from sVt. No sP buffer.
// grid (64,16): x=bh (fast -> balanced qb mix per CU), y=qb. 4 waves, 32 q rows each.
__global__ __launch_bounds__(256)
void attn_kernel(const bf16* __restrict__ qkv, const bf16* __restrict__ Vt, bf16* __restrict__ ctx)
{
    const int bh = blockIdx.x;
    const int qb = blockIdx.y;
    const int b = bh >> 4, h = bh & 15;
    const int t = threadIdx.x;
    const int wave = t >> 6, lane = t & 63;
    const int quad = lane >> 4, l16 = lane & 15;
    const long RS = 3072;
    const int ntiles = 2 * qb + 2;

    __shared__ bf16 sK[64 * 72];      // [t][d]
    __shared__ bf16 sVt[64 * 72];     // [d][t]

    // Q fragments (B-operand): B[k=d=quad*8+j][n=q=l16]
    bf16x8 qf[2][2];
#pragma unroll
    for (int rf = 0; rf < 2; rf++) {
        const bf16* qp = qkv + (long)(b * 2048 + qb * 128 + wave * 32 + rf * 16 + l16) * RS + h * 64 + quad * 8;
        qf[rf][0] = *(const bf16x8*)(qp);
        qf[rf][1] = *(const bf16x8*)(qp + 32);
    }
    f32x4 o[2][4];                     // O^T: lane q=l16, d=jb*16+quad*4+r
#pragma unroll
    for (int rf = 0; rf < 2; rf++)
#pragma unroll
        for (int jb = 0; jb < 4; jb++) o[rf][jb] = f32x4{0.f, 0.f, 0.f, 0.f};
    float m_i[2] = {NEGINF, NEGINF}, l_i[2] = {0.f, 0.f};
    const int qpos_base = qb * 128 + wave * 32;   // + rf*16 + l16

    const int cg = (t & 7) * 8, rr = t >> 3;
    const bf16* Kbase  = qkv + (long)(b * 2048) * RS + 1024 + h * 64;
    const bf16* Vtbase = Vt + ((long)bh * 64) * 2048;

    bf16x8 kreg[2], vreg[2];
#pragma unroll
    for (int p = 0; p < 2; p++) {   // prefetch tile 0
        kreg[p] = *(const bf16x8*)(Kbase + (long)(p * 32 + rr) * RS + cg);
        vreg[p] = *(const bf16x8*)(Vtbase + (long)(p * 32 + rr) * 2048 + cg);
    }

    for (int ti = 0; ti < ntiles; ti++) {
        __syncthreads();
#pragma unroll
        for (int p = 0; p < 2; p++) {
            *(bf16x8*)(&sK[(p * 32 + rr) * 72 + cg]) = kreg[p];
            *(bf16x8*)(&sVt[(p * 32 + rr) * 72 + cg]) = vreg[p];
        }
        __syncthreads();
        if (ti + 1 < ntiles) {
            int t0n = (ti + 1) * 64;
#pragma unroll
            for (int p = 0; p < 2; p++) {
                kreg[p] = *(const bf16x8*)(Kbase + (long)(t0n + p * 32 + rr) * RS + cg);
                vreg[p] = *(const bf16x8*)(Vtbase + (long)(p * 32 + rr) * 2048 + t0n + cg);
            }
        }
        const int t0 = ti * 64;

        // K fragments (A-operand): A[m=t=tt*16+l16][k=d=quad*8+j]
        bf16x8 kf[4][2];
#pragma unroll
        for (int tt = 0; tt < 4; tt++) {
            kf[tt][0] = *(const bf16x8*)(&sK[(tt * 16 + l16) * 72 + quad * 8]);
            kf[tt][1] = *(const bf16x8*)(&sK[(tt * 16 + l16) * 72 + 32 + quad * 8]);
        }
        // S^T + online softmax; produce P^T packed as K=16 B-operands
        bf16x4 pb[2][4];
#pragma unroll
        for (int rf = 0; rf < 2; rf++) {
            f32x4 sc[4];
#pragma unroll
            for (int tt = 0; tt < 4; tt++) {
                f32x4 s4 = f32x4{0.f, 0.f, 0.f, 0.f};
                s4 = __builtin_amdgcn_mfma_f32_16x16x32_bf16(kf[tt][0], qf[rf][0], s4, 0, 0, 0);
                s4 = __builtin_amdgcn_mfma_f32_16x16x32_bf16(kf[tt][1], qf[rf][1], s4, 0, 0, 0);
                sc[tt] = s4;
            }
            const int qpos = qpos_base + rf * 16 + l16;
            float mt = NEGINF;
#pragma unroll
            for (int tt = 0; tt < 4; tt++)
#pragma unroll
                for (int r = 0; r < 4; r++) {
                    int tcol = t0 + tt * 16 + quad * 4 + r;
                    float v = sc[tt][r] * 0.125f;
                    v = (tcol > qpos) ? NEGINF : v;
                    sc[tt][r] = v;
                    mt = fmaxf(mt, v);
                }
            mt = fmaxf(mt, __shfl_xor(mt, 16));
            mt = fmaxf(mt, __shfl_xor(mt, 32));
            float mn = fmaxf(m_i[rf], mt);
            float alpha = __expf(m_i[rf] - mn);
            m_i[rf] = mn;
            float lt = 0.f;
#pragma unroll
            for (int tt = 0; tt < 4; tt++)
#pragma unroll
                for (int r = 0; r < 4; r++) {
                    float p = __expf(sc[tt][r] - mn);
                    sc[tt][r] = p;
                    lt += p;
                }
            lt += __shfl_xor(lt, 16);
            lt += __shfl_xor(lt, 32);
            l_i[rf] = l_i[rf] * alpha + lt;
#pragma unroll
            for (int jb = 0; jb < 4; jb++)
#pragma unroll
                for (int r = 0; r < 4; r++) o[rf][jb][r] *= alpha;
#pragma unroll
            for (int tt = 0; tt < 4; tt++)
                pb[rf][tt] = bf16x4{(bf16)sc[tt][0], (bf16)sc[tt][1], (bf16)sc[tt][2], (bf16)sc[tt][3]};
        }
        // PV: O^T += V^T · P^T  (16x16x16, K-accumulate over tt)
#pragma unroll
        for (int jb = 0; jb < 4; jb++) {
#pragma unroll
            for (int tt = 0; tt < 4; tt++) {
                bf16x4 va = *(const bf16x4*)(&sVt[(jb * 16 + l16) * 72 + tt * 16 + quad * 4]);
                o[0][jb] = mfma16(va, pb[0][tt], o[0][jb]);
                o[1][jb] = mfma16(va, pb[1][tt], o[1][jb]);
            }
        }
    }
#pragma unroll
    for (int rf = 0; rf < 2; rf++) {
        float rl = 1.0f / l_i[rf];
        const long row = (long)(b * 2048 + qpos_base + rf * 16 + l16) * 1024 + h * 64;
#pragma unroll
        for (int jb = 0; jb < 4; jb++) {
            bf16x4 ov;
#pragma unroll
            for (int r = 0; r < 4; r++) ov[r] = (bf16)CLAMP(o[rf][jb][r] * rl);
            *(bf16x4*)(&ctx[row + jb * 16 + quad * 4]) = ov;
        }
    }
}

// ---------------- confidence head (f32) ----------------
__global__ __launch_bounds__(256)
void conf_partial(const float* __restrict__ xout, const float* __restrict__ cw, float* __restrict__ part)
{
    int blk = blockIdx.x;
    int b = blk >> 6, chunk = blk & 63;
    int t = threadIdx.x;
    int d0 = t * 4;
    f32x4 w = *(const f32x4*)(cw + d0);
    float acc = 0.f;
    for (int s = chunk * 32; s < chunk * 32 + 32; s++) {
        f32x4 v = *(const f32x4*)(xout + (long)(b * 2048 + s) * 1024 + d0);
        acc += v[0] * w[0] + v[1] * w[1] + v[2] * w[2] + v[3] * w[3];
    }
#pragma unroll
    for (int off = 32; off; off >>= 1) acc += __shfl_xor(acc, off);
    __shared__ float ls[4];
    if ((t & 63) == 0) ls[t >> 6] = acc;
    __syncthreads();
    if (t == 0) part[blk] = ls[0] + ls[1] + ls[2] + ls[3];
}

__global__ void conf_final(const float* __restrict__ part, const float* __restrict__ cb, float* __restrict__ outp)
{
    if (threadIdx.x == 0) {
        float accb = 0.f;
        for (int b = 0; b < 4; b++) {
            float s = 0.f;
            for (int i = 0; i < 64; i++) s += part[b * 64 + i];
            float z = s / 2048.0f + cb[0];
            accb += 1.0f / (1.0f + expf(-z));
        }
        outp[0] = accb * 0.25f;
    }
}

// ---------------- launch ----------------
// Workspace (1 MB = 1<<20), peak 96 MB + 1 KB, phase-disjoint aliasing:
//  [ 0, 8): WqkvT (ph1-3) -> W1T (ph6+)
//  [ 8,16): WoT (ph1-5)   -> W2T (ph6+)
//  [16,32): h (ph2-3) -> ctx (ph4-5) -> h2 (ph7-9)
//  [32,80): qkv (ph3-4); x1 f32 [32,64) ph5+ (qkv dead)
//  [80,96): Vt (ph3.5-4); a1h [64,96) ph8-9 (qkv tail + Vt dead)
//  [96MB):  part f32[256]
extern "C" void kernel_launch(void* const* d_in, const int* in_sizes, int n_in,
                              void* d_out, int out_size, void* d_ws, size_t ws_size,
                              hipStream_t stream)
{
    const int D = 1024, F = 4096, M = 8192;
    const size_t MB = 1u << 20;
    const float* x     = (const float*)d_in[0];
    const float* Wq    = (const float*)d_in[1];
    const float* Wk    = (const float*)d_in[2];
    const float* Wv    = (const float*)d_in[3];
    const float* Wo    = (const float*)d_in[4];
    const float* ln1w  = (const float*)d_in[5];
    const float* ln1b  = (const float*)d_in[6];
    const float* W1    = (const float*)d_in[7];
    const float* b1    = (const float*)d_in[8];
    const float* W2    = (const float*)d_in[9];
    const float* b2    = (const float*)d_in[10];
    const float* ln2w  = (const float*)d_in[11];
    const float* ln2b  = (const float*)d_in[12];
    const float* confw = (const float*)d_in[13];
    const float* confb = (const float*)d_in[14];
    float* out = (float*)d_out;

    char* ws = (char*)d_ws;
    bf16*  WqkvT = (bf16*)(ws);
    bf16*  WoT   = (bf16*)(ws + 8 * MB);
    bf16*  h     = (bf16*)(ws + 16 * MB);
    bf16*  qkv   = (bf16*)(ws + 32 * MB);
    bf16*  Vt    = (bf16*)(ws + 80 * MB);
    bf16*  ctx   = (bf16*)(ws + 16 * MB);
    float* x1    = (float*)(ws + 32 * MB);
    bf16*  h2    = (bf16*)(ws + 16 * MB);
    bf16*  W1T   = (bf16*)(ws);
    bf16*  W2T   = (bf16*)(ws + 8 * MB);
    bf16*  a1h   = (bf16*)(ws + 64 * MB);
    float* part  = (float*)(ws + 96 * MB);

    dim3 tb(32, 8);
    // ph1: QKV/Wo weight transposes in one launch
    transpose4_kernel<<<dim3(32, 32, 4), tb, 0, stream>>>(Wq, Wk, Wv, Wo, WqkvT, WoT);
    // ph2: LN1
    ln_kernel<<<M, 256, 0, stream>>>(x, ln1w, ln1b, h);
    // ph3: QKV projection
    gemm_bt<0><<<dim3(24, 64), 256, 0, stream>>>(h, D, WqkvT, D, M, 3 * D, D, nullptr, nullptr, qkv, 3 * D);
    // ph3.5: V transpose
    v_transpose<<<dim3(64, 2, 64), tb, 0, stream>>>(qkv, Vt);
    // ph4: attention (S^T flash; grid x=bh for balanced per-CU qb mix)
    attn_kernel<<<dim3(64, 16), 256, 0, stream>>>(qkv, Vt, ctx);
    // ph5: Wo projection + residual -> x1 f32
    gemm_bt<2><<<dim3(8, 64), 256, 0, stream>>>(ctx, D, WoT, D, M, D, D, nullptr, x, x1, D);
    // ph6: FFN weight transposes
    transpose_kernel<<<dim3(F / 32, D / 32), tb, 0, stream>>>(W1, W1T, D, F);
    transpose_kernel<<<dim3(D / 32, F / 32), tb, 0, stream>>>(W2, W2T, F, D);
    // ph7: LN2
    ln_kernel<<<M, 256, 0, stream>>>(x1, ln2w, ln2b, h2);
    // ph8: FFN half 1
    gemm_bt<1><<<dim3(16, 64), 256, 0, stream>>>(h2, D, W1T, D, M, 2048, D, b1, nullptr, a1h, 2048);
    gemm_bt<4><<<dim3(8, 64), 256, 0, stream>>>(a1h, 2048, W2T, F, M, D, 2048, nullptr, nullptr, x1, D);
    // ph9: FFN half 2 -> out f32
    gemm_bt<1><<<dim3(16, 64), 256, 0, stream>>>(h2, D, W1T + (size_t)2048 * D, D, M, 2048, D, b1 + 2048, nullptr, a1h, 2048);
    gemm_bt<3><<<dim3(8, 64), 256, 0, stream>>>(a1h, 2048, W2T + 2048, F, M, D, 2048, b2, x1, out, D);
    // ph10: confidence head
    conf_partial<<<256, 256, 0, stream>>>(out, confw, part);
    conf_final<<<1, 64, 0, stream>>>(part, confb, out + (size_t)M * D);
}